// Round 9
// baseline (267.853 us; speedup 1.0000x reference)
//
#include <hip/hip_runtime.h>
#include <stdint.h>

// Fused MLP decode, MFMA f16. ROUND 9: modulo-2 pipeline WIDENED to a PAIR
// of tiles per iteration (4 independent chains per scheduling region).
// Evidence so far:
//   - R4/R8: W1-in-LDS costs ~9.5us BOTH times (in-order lgkm queue drains
//     W1 reads ahead of Y reads every iteration) -> weights STAY in regs.
//   - R8: unified regs ~100 (<128) yet occupancy stuck at 25%: the register
//     ->occupancy-cliff theory is DEAD. Wave math (4096 waves x 30.5 iter,
//     97us => ~7600cy/iter vs ~800cy issue) says waves are ~85% stalled:
//     IN-WAVE LATENCY is the limiter at fixed ~4 waves/SIMD.
//   - R7 (phase interleave) was the only structural win since R3 -> widen it.
// Iteration k: phase2(pair k-1: tiles a',b') ; phase1(pair k: tiles a,b).
// All four phase bodies touch different tiles -> scheduler overlaps their
// ~400cy chains inside one wave. H: [wave][2 pairbuf][2 tile][16][72]
// (36864 B/block, 4 blocks/CU). Merged 128B store: q=0 lanes store tile a,
// q=1 tile b. Packed f16 bias/Wout constants (R8, -16 regs) kept.
// Math per tile unchanged from R7 (passed): swapped L1 mfma(w1,Y), per-lane
// Wout dot + 2 shfl_xor, scale-folded u-domain silu, Chebyshev features,
// tix/rho 2 pairs ahead + emb 1 pair ahead prefetch, grid 1024.

typedef _Float16 half8  __attribute__((ext_vector_type(8)));
typedef _Float16 half4v __attribute__((ext_vector_type(4)));
typedef _Float16 half2v __attribute__((ext_vector_type(2)));
typedef float f32x4 __attribute__((ext_vector_type(4)));

#define LOG2E 1.44269504088896340736f
#define NLN2  -0.6931471805599453f         // -ln2 = 1/(-log2e)
#define CSCL  -1.44269504088896340736f     // c = -log2e
#define BASE_LOGIT -0.84729786038720367f   // log(0.3/0.7)
#define CSANMAX 28700.0f
#define IC_VAL 8610.0f                     // 0.3 * 28700

__device__ __forceinline__ float fast_exp2(float x) { return __builtin_amdgcn_exp2f(x); }
__device__ __forceinline__ float fast_rcp(float x)  { return __builtin_amdgcn_rcpf(x); }
// u-domain pair silu: inputs u0,u1 (= c*x). outputs p = u*sigma = c*silu(x).
__device__ __forceinline__ void usilu2(float u0, float u1, float& p0, float& p1) {
  const float d0 = 1.0f + fast_exp2(u0);
  const float d1 = 1.0f + fast_exp2(u1);
  const float r  = fast_rcp(d0 * d1);
  p0 = u0 * d1 * r;
  p1 = u1 * d0 * r;
}
__device__ __forceinline__ half2v pkh(float a, float b) {
  return __builtin_bit_cast(half2v, __builtin_amdgcn_cvt_pkrtz(a, b));
}

union H8 { half8 v8; half2v v2[4]; half4v v4[2]; };
union H4 { half4v v4; half2v v2[2]; };

__global__ __launch_bounds__(256, 3) void mlp_kernel(
    const int* __restrict__ tix, const float* __restrict__ rho,
    const float* __restrict__ emb, const float* __restrict__ W0,
    const float* __restrict__ b0, const float* __restrict__ W1,
    const float* __restrict__ b1, const float* __restrict__ Wout,
    const float* __restrict__ bout, float* __restrict__ out, int ntiles)
{
  // Weight staging (init only, 16384 B) unions into the pair-double-buffered
  // per-wave H (4 waves x 2 pairbuf x 2 tiles x 16 x 72 halfs = 36864 B).
  __shared__ __align__(16) union {
    _Float16 stage[2][2][4][64][8];
    _Float16 H[4][2][2][16][72];    // row stride 144 B -> 2-way banks (free)
  } shA;

  const int tid  = threadIdx.x;
  const int wid  = tid >> 6;
  const int lane = tid & 63;
  const int m    = lane & 15;
  const int q    = lane >> 4;

  // ---- init: wave 0 builds the swizzled weight fragments ----
  // content B[k=s*32+q*8+j][n=t*16+m]; same lane layout serves as A-op
  // (=> W^T) or B-op. L0 feature rows PERMUTED: k-window 32..63 =
  // [cos1..8|sin1..8|rho,b0(1.0),0pad]. L0 fragments PRE-SCALED by c.
  if (wid == 0) {
#pragma unroll
    for (int t = 0; t < 4; ++t) {
#pragma unroll
      for (int s = 0; s < 2; ++s) {
        half8 f0, f1;
#pragma unroll
        for (int j = 0; j < 8; ++j) {
          const int k = s * 32 + q * 8 + j;
          const int n = t * 16 + m;
          float v0;
          if (k < 32) {
            v0 = W0[k * 64 + n];
          } else {
            const int kn = k - 32;
            v0 = (kn < 16) ? W0[(33 + kn) * 64 + n]
               : (kn == 16) ? W0[32 * 64 + n]
               : (kn == 17) ? b0[n] : 0.0f;
          }
          f0[j] = (_Float16)(CSCL * v0);
          f1[j] = (_Float16)W1[k * 64 + n];   // W1 UNSCALED (c rides through p)
        }
        *(half8*)&shA.stage[0][s][t][lane][0] = f0;
        *(half8*)&shA.stage[1][s][t][lane][0] = f1;
      }
    }
  }

  // ---- persistent epilogue constants, PACKED f16 (swapped L1 layout) ----
  // lane (q,m) owns hidden h = t*16 + q*4 + r; consumed via v_fma_mix.
  half2v biash[8];   // c * b1[h]
  half2v wouth[8];   // -ln2 * Wout[h]
#pragma unroll
  for (int t = 0; t < 4; ++t) {
    const f32x4 bv = *(const f32x4*)(b1 + t * 16 + q * 4);
    const f32x4 wv = *(const f32x4*)(Wout + t * 16 + q * 4);
    biash[t * 2]     = pkh(CSCL * bv[0], CSCL * bv[1]);
    biash[t * 2 + 1] = pkh(CSCL * bv[2], CSCL * bv[3]);
    wouth[t * 2]     = pkh(NLN2 * wv[0], NLN2 * wv[1]);
    wouth[t * 2 + 1] = pkh(NLN2 * wv[2], NLN2 * wv[3]);
  }
  const float boutBL = bout[0] + BASE_LOGIT;

  __syncthreads();   // staged weights visible

  // ---- hoist ALL weight fragments to registers (loop-invariant) ----
  half8 w0A[4], w0B[4], w1A[4], w1B[4];
#pragma unroll
  for (int t = 0; t < 4; ++t) {
    w0A[t] = *(const half8*)&shA.stage[0][0][t][lane][0];
    w0B[t] = *(const half8*)&shA.stage[0][1][t][lane][0];
    w1A[t] = *(const half8*)&shA.stage[1][0][t][lane][0];
    w1B[t] = *(const half8*)&shA.stage[1][1][t][lane][0];
  }

  __syncthreads();   // stage reads done; H may overwrite

  const f32x4 z = {0.0f, 0.0f, 0.0f, 0.0f};
  const int W = gridDim.x * 4;            // total waves
  const int npairs = ntiles >> 1;         // ntiles is even (n % 32 == 0)
  int p = blockIdx.x * 4 + wid;           // pair index (tiles 2p, 2p+1)
  if (p >= npairs) return;                // after both barriers: safe
  const int plim = npairs - 1;

  // ---- phase1: feat -> L0 -> silu -> Hdst (one tile) ----
  auto phase1 = [&](float rhp, half8 X0v, _Float16 (*Hdst)[72]) {
    const float rev = 0.5f * rhp;  // v_sin/v_cos take revolutions
    const float c1  = __builtin_amdgcn_cosf(rev);
    const float s1f = __builtin_amdgcn_sinf(rev);
    const float tc  = 2.0f * c1;
    const float x1v = (q == 0) ? c1 : ((q == 1) ? s1f : 0.0f);
    const float x0v = (q == 0) ? 1.0f : 0.0f;
    const float x2v = tc * x1v - x0v;
    const float x3v = tc * x2v - x1v;
    const float x4v = tc * x3v - x2v;
    const float x5v = tc * x4v - x3v;
    const float x6v = tc * x5v - x4v;
    const float x7v = tc * x6v - x5v;
    const float x8v = tc * x7v - x6v;
    H8 X1;
    X1.v2[0] = (q == 2) ? pkh(rhp, 1.0f) : pkh(x1v, x2v);  // q==2: (rho, b0-slot)
    X1.v2[1] = pkh(x3v, x4v);
    X1.v2[2] = pkh(x5v, x6v);
    X1.v2[3] = pkh(x7v, x8v);

    f32x4 acc[4];
#pragma unroll
    for (int t = 0; t < 4; ++t) {
      f32x4 a = __builtin_amdgcn_mfma_f32_16x16x32_f16(w0A[t], X0v, z, 0, 0, 0);
      a = __builtin_amdgcn_mfma_f32_16x16x32_f16(w0B[t], X1.v8, a, 0, 0, 0);
      acc[t] = a;
    }
#pragma unroll
    for (int t = 0; t < 4; ++t) {
      float p0, p1, p2, p3;
      usilu2(acc[t][0], acc[t][1], p0, p1);
      usilu2(acc[t][2], acc[t][3], p2, p3);
      H4 hh;
      hh.v2[0] = pkh(p0, p1);
      hh.v2[1] = pkh(p2, p3);
      *(half4v*)&Hdst[m][t * 16 + q * 4] = hh.v4;
    }
  };

  // ---- phase2pair: L1+dot for BOTH tiles of a pair; merged 128B store ----
  auto phase2pair = [&](_Float16 (*Hsrc)[16][72], int pP, int taP, int tbP) {
    float dots0, dots1;
#pragma unroll
    for (int s = 0; s < 2; ++s) {
      const half8 Y0 = *(const half8*)&Hsrc[s][m][q * 8];      // 1 iter old
      const half8 Y1 = *(const half8*)&Hsrc[s][m][32 + q * 8];
      f32x4 acc[4];
#pragma unroll
      for (int t = 0; t < 4; ++t) {
        f32x4 a = __builtin_amdgcn_mfma_f32_16x16x32_f16(w1A[t], Y0, z, 0, 0, 0);
        a = __builtin_amdgcn_mfma_f32_16x16x32_f16(w1B[t], Y1, a, 0, 0, 0);
        acc[t] = a;
      }
      float dA = 0.0f, dB = 0.0f;
#pragma unroll
      for (int t = 0; t < 4; ++t) {
        float p0, p1, p2, p3;
        const float u0 = (float)biash[t * 2][0]     + acc[t][0];  // v_fma_mix
        const float u1 = (float)biash[t * 2][1]     + acc[t][1];
        const float u2 = (float)biash[t * 2 + 1][0] + acc[t][2];
        const float u3 = (float)biash[t * 2 + 1][1] + acc[t][3];
        usilu2(u0, u1, p0, p1);
        usilu2(u2, u3, p2, p3);
        dA = fmaf(p0, (float)wouth[t * 2][0],     dA);
        dB = fmaf(p1, (float)wouth[t * 2][1],     dB);
        dA = fmaf(p2, (float)wouth[t * 2 + 1][0], dA);
        dB = fmaf(p3, (float)wouth[t * 2 + 1][1], dB);
      }
      float dot = dA + dB;
      dot += __shfl_xor(dot, 16, 64);
      dot += __shfl_xor(dot, 32, 64);
      if (s == 0) dots0 = dot; else dots1 = dot;
    }
    // merged store: q==0 lanes -> tile a (16 floats), q==1 -> tile b.
    const float dsel = (q & 1) ? dots1 : dots0;
    const int   tsel = (q & 1) ? tbP : taP;
    const float theta = fast_rcp(1.0f + fast_exp2(-LOG2E * (dsel + boutBL)));
    const float val = (tsel == 0) ? IC_VAL : theta * CSANMAX;
    if (q < 2) out[pP * 32 + q * 16 + m] = val;
  };

  // ---- prologue: fill the pipe with pair p ----
  int   tCa = tix[p * 32 + m],      tCb = tix[p * 32 + 16 + m];
  float rCa = rho[p * 32 + m],      rCb = rho[p * 32 + 16 + m];
  const int p1 = min(p + W, plim);
  int   tNa = tix[p1 * 32 + m],     tNb = tix[p1 * 32 + 16 + m];
  float rNa = rho[p1 * 32 + m],     rNb = rho[p1 * 32 + 16 + m];

  H8 X0Ca, X0Cb;
  {
    const int ia = min(max(tCa - 1, 0), 510);
    const int ib = min(max(tCb - 1, 0), 510);
    const float* ea = emb + (size_t)ia * 32 + q * 8;
    const float* eb = emb + (size_t)ib * 32 + q * 8;
    const f32x4 a0 = *(const f32x4*)ea, a1 = *(const f32x4*)(ea + 4);
    const f32x4 b0v = *(const f32x4*)eb, b1v = *(const f32x4*)(eb + 4);
    X0Ca.v2[0] = pkh(a0[0], a0[1]); X0Ca.v2[1] = pkh(a0[2], a0[3]);
    X0Ca.v2[2] = pkh(a1[0], a1[1]); X0Ca.v2[3] = pkh(a1[2], a1[3]);
    X0Cb.v2[0] = pkh(b0v[0], b0v[1]); X0Cb.v2[1] = pkh(b0v[2], b0v[3]);
    X0Cb.v2[2] = pkh(b1v[0], b1v[1]); X0Cb.v2[3] = pkh(b1v[2], b1v[3]);
  }
  phase1(rCa, X0Ca.v8, shA.H[wid][0][0]);
  phase1(rCb, X0Cb.v8, shA.H[wid][0][1]);
  int pPrev = p, taP = tCa, tbP = tCb;
  {
    const int ia = min(max(tNa - 1, 0), 510);
    const int ib = min(max(tNb - 1, 0), 510);
    const float* ea = emb + (size_t)ia * 32 + q * 8;
    const float* eb = emb + (size_t)ib * 32 + q * 8;
    const f32x4 a0 = *(const f32x4*)ea, a1 = *(const f32x4*)(ea + 4);
    const f32x4 b0v = *(const f32x4*)eb, b1v = *(const f32x4*)(eb + 4);
    X0Ca.v2[0] = pkh(a0[0], a0[1]); X0Ca.v2[1] = pkh(a0[2], a0[3]);
    X0Ca.v2[2] = pkh(a1[0], a1[1]); X0Ca.v2[3] = pkh(a1[2], a1[3]);
    X0Cb.v2[0] = pkh(b0v[0], b0v[1]); X0Cb.v2[1] = pkh(b0v[2], b0v[3]);
    X0Cb.v2[2] = pkh(b1v[0], b1v[1]); X0Cb.v2[3] = pkh(b1v[2], b1v[3]);
  }
  tCa = tNa; rCa = rNa; tCb = tNb; rCb = rNb;
  {
    const int p2i = min(p + 2 * W, plim);
    tNa = tix[p2i * 32 + m]; rNa = rho[p2i * 32 + m];
    tNb = tix[p2i * 32 + 16 + m]; rNb = rho[p2i * 32 + 16 + m];
  }
  int cur = 1;
  p += W;

  // ---- steady state: phase2(pair k-1) ; phase1(pair k, both tiles) ----
  while (p < npairs) {
    // prefetch tix/rho 2 pairs ahead (clamped, branchless)
    const int pf = min(p + 2 * W, plim);
    const int   tQa = tix[pf * 32 + m],      tQb = tix[pf * 32 + 16 + m];
    const float rQa = rho[pf * 32 + m],      rQb = rho[pf * 32 + 16 + m];
    // emb loads for NEXT pair (tNa/tNb arrived >=1 iteration ago)
    const int ia = min(max(tNa - 1, 0), 510);
    const int ib = min(max(tNb - 1, 0), 510);
    const float* ea = emb + (size_t)ia * 32 + q * 8;
    const float* eb = emb + (size_t)ib * 32 + q * 8;
    const f32x4 eA0 = *(const f32x4*)ea, eA1 = *(const f32x4*)(ea + 4);
    const f32x4 eB0 = *(const f32x4*)eb, eB1 = *(const f32x4*)(eb + 4);

    phase2pair(shA.H[wid][cur ^ 1], pPrev, taP, tbP);   // finish pair k-1
    phase1(rCa, X0Ca.v8, shA.H[wid][cur][0]);           // start pair k
    phase1(rCb, X0Cb.v8, shA.H[wid][cur][1]);

    pPrev = p; taP = tCa; tbP = tCb;
    X0Ca.v2[0] = pkh(eA0[0], eA0[1]); X0Ca.v2[1] = pkh(eA0[2], eA0[3]);
    X0Ca.v2[2] = pkh(eA1[0], eA1[1]); X0Ca.v2[3] = pkh(eA1[2], eA1[3]);
    X0Cb.v2[0] = pkh(eB0[0], eB0[1]); X0Cb.v2[1] = pkh(eB0[2], eB0[3]);
    X0Cb.v2[2] = pkh(eB1[0], eB1[1]); X0Cb.v2[3] = pkh(eB1[2], eB1[3]);
    tCa = tNa; rCa = rNa; tCb = tNb; rCb = rNb;
    tNa = tQa; rNa = rQa; tNb = tQb; rNb = rQb;
    cur ^= 1;
    p += W;
  }

  // ---- epilogue: drain the last pair ----
  phase2pair(shA.H[wid][cur ^ 1], pPrev, taP, tbP);
}

extern "C" void kernel_launch(void* const* d_in, const int* in_sizes, int n_in,
                              void* d_out, int out_size, void* d_ws, size_t ws_size,
                              hipStream_t stream) {
  const int*   tix  = (const int*)d_in[0];
  const float* rho  = (const float*)d_in[1];
  const float* emb  = (const float*)d_in[2];
  const float* W0   = (const float*)d_in[3];
  const float* b0   = (const float*)d_in[4];
  const float* W1   = (const float*)d_in[5];
  const float* b1   = (const float*)d_in[6];
  const float* Wout = (const float*)d_in[7];
  const float* bout = (const float*)d_in[8];
  float* outp = (float*)d_out;

  const int n      = in_sizes[0];    // 2,000,000 (divisible by 32)
  const int ntiles = n / 16;         // 125,000 tiles -> 62,500 pairs

  // 4-wave blocks, 36864 B LDS -> 4 blocks/CU. Grid 1024 (R3 winner).
  int grid = 1024;
  const int npairs = ntiles >> 1;
  const int maxg = (npairs + 3) / 4;
  if (grid > maxg) grid = maxg;
  mlp_kernel<<<dim3(grid), dim3(256), 0, stream>>>(
      tix, rho, emb, W0, b0, W1, b1, Wout, bout, outp, ntiles);
}

// Round 11
// 168.015 us; speedup vs baseline: 1.5942x; 1.5942x over previous
//
#include <hip/hip_runtime.h>
#include <stdint.h>

// Fused MLP decode, MFMA f16. ROUND 11 (= R10 resubmit; container infra
// failure, no counters; hmap identity re-audited and confirmed exact).
// ZERO-LDS steady loop:
//   REGISTER-DIRECT L1 via hidden-permutation (hmap). The hidden dim is
//   contraction-internal, so we may permute it freely as long as W1's rows
//   agree. Choosing hmap(k)=(s*2+(j>>2))*16 + q*4 + (j&3) makes L0's
//   accumulator output (lane (q,m) holds P[t*16+q*4+j][m]) ALREADY a valid
//   L1 B-fragment: Y0=[hh0|hh1], Y1=[hh2|hh3] -- pure register concat.
//   Deletes the whole H round trip: 4 ds_write + 2 ds_read + RAW wait +
//   H buffers + double-buffer scaffolding. Loop DS ops: only 2 shfl_xor.
//   (f32 fmaf dot kept -- NOT an f16 MFMA dot -- to hold absmax at 64.)
// Kept from prior rounds (all validated): weights AGPR-resident (R4/R8:
// W1-in-LDS costs ~9.5us), packed f16 bias/Wout consts (R8), swapped L1
// mfma(w1,Y) with b1 via v_fma_mix, scale-folded u-domain silu, Chebyshev
// features, tix/rho 2-ahead + emb 1-ahead prefetch, grid 1024, lb(256,3).

typedef _Float16 half8  __attribute__((ext_vector_type(8)));
typedef _Float16 half4v __attribute__((ext_vector_type(4)));
typedef _Float16 half2v __attribute__((ext_vector_type(2)));
typedef float f32x4 __attribute__((ext_vector_type(4)));

#define LOG2E 1.44269504088896340736f
#define NLN2  -0.6931471805599453f         // -ln2 = 1/(-log2e)
#define CSCL  -1.44269504088896340736f     // c = -log2e
#define BASE_LOGIT -0.84729786038720367f   // log(0.3/0.7)
#define CSANMAX 28700.0f
#define IC_VAL 8610.0f                     // 0.3 * 28700

__device__ __forceinline__ float fast_exp2(float x) { return __builtin_amdgcn_exp2f(x); }
__device__ __forceinline__ float fast_rcp(float x)  { return __builtin_amdgcn_rcpf(x); }
// u-domain pair silu: inputs u0,u1 (= c*x). outputs p = u*sigma = c*silu(x).
__device__ __forceinline__ void usilu2(float u0, float u1, float& p0, float& p1) {
  const float d0 = 1.0f + fast_exp2(u0);
  const float d1 = 1.0f + fast_exp2(u1);
  const float r  = fast_rcp(d0 * d1);
  p0 = u0 * d1 * r;
  p1 = u1 * d0 * r;
}
__device__ __forceinline__ half2v pkh(float a, float b) {
  return __builtin_bit_cast(half2v, __builtin_amdgcn_cvt_pkrtz(a, b));
}

union H8 { half8 v8; half2v v2[4]; half4v v4[2]; };
union H4 { half4v v4; half2v v2[2]; };

__global__ __launch_bounds__(256, 3) void mlp_kernel(
    const int* __restrict__ tix, const float* __restrict__ rho,
    const float* __restrict__ emb, const float* __restrict__ W0,
    const float* __restrict__ b0, const float* __restrict__ W1,
    const float* __restrict__ b1, const float* __restrict__ Wout,
    const float* __restrict__ bout, float* __restrict__ out, int ntiles)
{
  // Weight staging ONLY (init, 16384 B). No H buffer exists anymore.
  __shared__ __align__(16) _Float16 stage[2][2][4][64][8];

  const int tid  = threadIdx.x;
  const int wid  = tid >> 6;
  const int lane = tid & 63;
  const int m    = lane & 15;
  const int q    = lane >> 4;

  // ---- init: wave 0 builds the swizzled weight fragments ----
  // W0 (A-op, => W0^T): element (s,t,lane,j) = c * W0[k][n], k=s*32+q*8+j,
  // n=t*16+m; feature rows PERMUTED (k-window 32..63 =
  // [cos1..8|sin1..8|rho,b0(1.0),0pad]); pre-scaled by c=-log2e.
  // W1 (A-op, => W1^T): rows permuted by hmap so that L1's B-operand is
  // L0's register output directly: hmap(k) = (s*2+(j>>2))*16 + q*4 + (j&3).
  if (wid == 0) {
#pragma unroll
    for (int t = 0; t < 4; ++t) {
#pragma unroll
      for (int s = 0; s < 2; ++s) {
        half8 f0, f1;
#pragma unroll
        for (int j = 0; j < 8; ++j) {
          const int k = s * 32 + q * 8 + j;
          const int n = t * 16 + m;
          float v0;
          if (k < 32) {
            v0 = W0[k * 64 + n];
          } else {
            const int kn = k - 32;
            v0 = (kn < 16) ? W0[(33 + kn) * 64 + n]
               : (kn == 16) ? W0[32 * 64 + n]
               : (kn == 17) ? b0[n] : 0.0f;
          }
          f0[j] = (_Float16)(CSCL * v0);
          const int hm = (s * 2 + (j >> 2)) * 16 + q * 4 + (j & 3);
          f1[j] = (_Float16)W1[hm * 64 + n];   // W1 UNSCALED, hmap-permuted
        }
        *(half8*)&stage[0][s][t][lane][0] = f0;
        *(half8*)&stage[1][s][t][lane][0] = f1;
      }
    }
  }

  // ---- persistent epilogue constants, PACKED f16 (swapped L1 layout) ----
  // lane (q,m) owns out-hidden h = t*16 + q*4 + r; consumed via v_fma_mix.
  half2v biash[8];   // c * b1[h]
  half2v wouth[8];   // -ln2 * Wout[h]
#pragma unroll
  for (int t = 0; t < 4; ++t) {
    const f32x4 bv = *(const f32x4*)(b1 + t * 16 + q * 4);
    const f32x4 wv = *(const f32x4*)(Wout + t * 16 + q * 4);
    biash[t * 2]     = pkh(CSCL * bv[0], CSCL * bv[1]);
    biash[t * 2 + 1] = pkh(CSCL * bv[2], CSCL * bv[3]);
    wouth[t * 2]     = pkh(NLN2 * wv[0], NLN2 * wv[1]);
    wouth[t * 2 + 1] = pkh(NLN2 * wv[2], NLN2 * wv[3]);
  }
  const float boutBL = bout[0] + BASE_LOGIT;

  __syncthreads();   // staged weights visible

  // ---- hoist ALL weight fragments to registers (loop-invariant) ----
  half8 w0A[4], w0B[4], w1A[4], w1B[4];
#pragma unroll
  for (int t = 0; t < 4; ++t) {
    w0A[t] = *(const half8*)&stage[0][0][t][lane][0];
    w0B[t] = *(const half8*)&stage[0][1][t][lane][0];
    w1A[t] = *(const half8*)&stage[1][0][t][lane][0];
    w1B[t] = *(const half8*)&stage[1][1][t][lane][0];
  }
  // stage is never written again; no second barrier needed.

  const f32x4 z = {0.0f, 0.0f, 0.0f, 0.0f};
  const int S = gridDim.x * 4;

  int tg = blockIdx.x * 4 + wid;
  if (tg >= ntiles) return;          // after the barrier: safe
  const int lim = ntiles - 1;

  // ---- pipeline preload: tix/rho for tiles tg and tg+S; emb for tg ----
  int   tC = tix[tg * 16 + m];
  float rC = rho[tg * 16 + m];
  const int tg1 = min(tg + S, lim);
  int   tN = tix[tg1 * 16 + m];
  float rN = rho[tg1 * 16 + m];
  H8 X0C;
  {
    const int idx = min(max(tC - 1, 0), 510);
    const float* e = emb + (size_t)idx * 32 + q * 8;
    const f32x4 e0 = *(const f32x4*)e;
    const f32x4 e1 = *(const f32x4*)(e + 4);
    X0C.v2[0] = pkh(e0[0], e0[1]); X0C.v2[1] = pkh(e0[2], e0[3]);
    X0C.v2[2] = pkh(e1[0], e1[1]); X0C.v2[3] = pkh(e1[2], e1[3]);
  }

  while (true) {
    // ---- prefetch: tix/rho 2 tiles ahead; emb 1 tile ahead (tN is old) ----
    const int tg2 = min(tg + 2 * S, lim);
    const int   tQ = tix[tg2 * 16 + m];
    const float rQ = rho[tg2 * 16 + m];
    const int idxN = min(max(tN - 1, 0), 510);
    const float* ern = emb + (size_t)idxN * 32 + q * 8;
    const f32x4 eN0 = *(const f32x4*)ern;
    const f32x4 eN1 = *(const f32x4*)(ern + 4);

    // ---- feature fragment, in-layout Chebyshev chain ----
    const float rev = 0.5f * rC;   // v_sin/v_cos take revolutions
    const float c1  = __builtin_amdgcn_cosf(rev);
    const float s1f = __builtin_amdgcn_sinf(rev);
    const float tc  = 2.0f * c1;
    const float x1v = (q == 0) ? c1 : ((q == 1) ? s1f : 0.0f);
    const float x0v = (q == 0) ? 1.0f : 0.0f;
    const float x2v = tc * x1v - x0v;
    const float x3v = tc * x2v - x1v;
    const float x4v = tc * x3v - x2v;
    const float x5v = tc * x4v - x3v;
    const float x6v = tc * x5v - x4v;
    const float x7v = tc * x6v - x5v;
    const float x8v = tc * x7v - x6v;
    H8 X1;
    X1.v2[0] = (q == 2) ? pkh(rC, 1.0f) : pkh(x1v, x2v);  // q==2: (rho, b0-slot)
    X1.v2[1] = pkh(x3v, x4v);
    X1.v2[2] = pkh(x5v, x6v);
    X1.v2[3] = pkh(x7v, x8v);

    // ---- L0 (A=W0^T, B=X): acc = u = c * preact0, [hidden][point] ----
    f32x4 acc[4];
#pragma unroll
    for (int t = 0; t < 4; ++t) {
      f32x4 a = __builtin_amdgcn_mfma_f32_16x16x32_f16(w0A[t], X0C.v8, z, 0, 0, 0);
      a = __builtin_amdgcn_mfma_f32_16x16x32_f16(w0B[t], X1.v8, a, 0, 0, 0);
      acc[t] = a;
    }
    // silu -> packed f16, registers only
    H4 hh[4];
#pragma unroll
    for (int t = 0; t < 4; ++t) {
      float p0, p1, p2, p3;
      usilu2(acc[t][0], acc[t][1], p0, p1);
      usilu2(acc[t][2], acc[t][3], p2, p3);
      hh[t].v2[0] = pkh(p0, p1);
      hh[t].v2[1] = pkh(p2, p3);
    }
    // ---- register-direct L1 B-operand (hmap makes this exact) ----
    H8 Y0, Y1;
    Y0.v4[0] = hh[0].v4; Y0.v4[1] = hh[1].v4;
    Y1.v4[0] = hh[2].v4; Y1.v4[1] = hh[3].v4;

    // ---- L1 (A=W1^T hmap-staged, B=Y): acc = [out-hidden][point] ----
#pragma unroll
    for (int t = 0; t < 4; ++t) {
      f32x4 a = __builtin_amdgcn_mfma_f32_16x16x32_f16(w1A[t], Y0.v8, z, 0, 0, 0);
      a = __builtin_amdgcn_mfma_f32_16x16x32_f16(w1B[t], Y1.v8, a, 0, 0, 0);
      acc[t] = a;
    }
    // bias (v_fma_mix) + silu + per-lane f32 dot over this lane's 16 h
    float dA = 0.0f, dB = 0.0f;
#pragma unroll
    for (int t = 0; t < 4; ++t) {
      float p0, p1, p2, p3;
      const float u0 = (float)biash[t * 2][0]     + acc[t][0];
      const float u1 = (float)biash[t * 2][1]     + acc[t][1];
      const float u2 = (float)biash[t * 2 + 1][0] + acc[t][2];
      const float u3 = (float)biash[t * 2 + 1][1] + acc[t][3];
      usilu2(u0, u1, p0, p1);
      usilu2(u2, u3, p2, p3);
      dA = fmaf(p0, (float)wouth[t * 2][0],     dA);
      dB = fmaf(p1, (float)wouth[t * 2][1],     dB);
      dA = fmaf(p2, (float)wouth[t * 2 + 1][0], dA);
      dB = fmaf(p3, (float)wouth[t * 2 + 1][1], dB);
    }
    float dot = dA + dB;
    dot += __shfl_xor(dot, 16, 64);   // the only DS ops left in the loop
    dot += __shfl_xor(dot, 32, 64);

    // ---- epilogue: precise sigmoid, 64B store by q==0 lanes ----
    const float theta = fast_rcp(1.0f + fast_exp2(-LOG2E * (dot + boutBL)));
    const float val = (tC == 0) ? IC_VAL : theta * CSANMAX;
    if (q == 0) out[tg * 16 + m] = val;

    // ---- advance pipeline ----
    const int tgn = tg + S;
    if (tgn >= ntiles) break;
    tg = tgn;
    X0C.v2[0] = pkh(eN0[0], eN0[1]); X0C.v2[1] = pkh(eN0[2], eN0[3]);
    X0C.v2[2] = pkh(eN1[0], eN1[1]); X0C.v2[3] = pkh(eN1[2], eN1[3]);
    tC = tN; rC = rN;
    tN = tQ; rN = rQ;
  }
}

extern "C" void kernel_launch(void* const* d_in, const int* in_sizes, int n_in,
                              void* d_out, int out_size, void* d_ws, size_t ws_size,
                              hipStream_t stream) {
  const int*   tix  = (const int*)d_in[0];
  const float* rho  = (const float*)d_in[1];
  const float* emb  = (const float*)d_in[2];
  const float* W0   = (const float*)d_in[3];
  const float* b0   = (const float*)d_in[4];
  const float* W1   = (const float*)d_in[5];
  const float* b1   = (const float*)d_in[6];
  const float* Wout = (const float*)d_in[7];
  const float* bout = (const float*)d_in[8];
  float* outp = (float*)d_out;

  const int n      = in_sizes[0];    // 2,000,000 (divisible by 16)
  const int ntiles = n / 16;         // 125,000 tiles of 16 points

  // 4-wave blocks, 16384 B LDS (init staging only). Grid 1024 (R3 winner).
  int grid = 1024;
  const int maxg = (ntiles + 3) / 4;
  if (grid > maxg) grid = maxg;
  mlp_kernel<<<dim3(grid), dim3(256), 0, stream>>>(
      tix, rho, emb, W0, b0, W1, b1, Wout, bout, outp, ntiles);
}

// Round 12
// 163.015 us; speedup vs baseline: 1.6431x; 1.0307x over previous
//
#include <hip/hip_runtime.h>
#include <stdint.h>

// Fused MLP decode, MFMA f16. ROUND 12: ZERO-LDS + MODULO-2 INTERLEAVE.
// Ledger: R7 (interleave, LDS H) = 97us; R11 (zero-LDS, serial) = 106us;
// R6-V3 (DS-RAW removal) = null. Conclusion: DS never cost anything; the
// interleave's two independent per-iteration chains are worth ~9us. This
// round composes both: register-direct L1 (hmap identity, R11-validated)
// makes the cross-iteration state just Y0p/Y1p (8 VGPRs) + 2 scalars --
// far cheaper than R7's LDS dbuf or R9's pair-widening (spilled, +40 regs).
// Iteration k:
//   phase2(tile k-1): L1 mfma(w1, Ycarried) -> bias+silu -> dot -> reduce
//                     -> sigmoid -> store     (no memory deps at all)
//   phase1(tile k)  : feat -> L0 mfma -> silu -> pack -> Y carried
// Kept (validated): weights AGPR-resident (R4/R8), hmap-permuted W1 (R11,
// exact), packed f16 bias/Wout consts (R8), scale-folded u-domain silu,
// Chebyshev features, tix/rho 2-ahead + emb 1-ahead prefetch, grid 1024,
// lb(256,3). Loop has ZERO ds ops and ZERO barriers.

typedef _Float16 half8  __attribute__((ext_vector_type(8)));
typedef _Float16 half4v __attribute__((ext_vector_type(4)));
typedef _Float16 half2v __attribute__((ext_vector_type(2)));
typedef float f32x4 __attribute__((ext_vector_type(4)));

#define LOG2E 1.44269504088896340736f
#define NLN2  -0.6931471805599453f         // -ln2 = 1/(-log2e)
#define CSCL  -1.44269504088896340736f     // c = -log2e
#define BASE_LOGIT -0.84729786038720367f   // log(0.3/0.7)
#define CSANMAX 28700.0f
#define IC_VAL 8610.0f                     // 0.3 * 28700

__device__ __forceinline__ float fast_exp2(float x) { return __builtin_amdgcn_exp2f(x); }
__device__ __forceinline__ float fast_rcp(float x)  { return __builtin_amdgcn_rcpf(x); }
// u-domain pair silu: inputs u0,u1 (= c*x). outputs p = u*sigma = c*silu(x).
__device__ __forceinline__ void usilu2(float u0, float u1, float& p0, float& p1) {
  const float d0 = 1.0f + fast_exp2(u0);
  const float d1 = 1.0f + fast_exp2(u1);
  const float r  = fast_rcp(d0 * d1);
  p0 = u0 * d1 * r;
  p1 = u1 * d0 * r;
}
__device__ __forceinline__ half2v pkh(float a, float b) {
  return __builtin_bit_cast(half2v, __builtin_amdgcn_cvt_pkrtz(a, b));
}

union H8 { half8 v8; half2v v2[4]; half4v v4[2]; };
union H4 { half4v v4; half2v v2[2]; };

__global__ __launch_bounds__(256, 3) void mlp_kernel(
    const int* __restrict__ tix, const float* __restrict__ rho,
    const float* __restrict__ emb, const float* __restrict__ W0,
    const float* __restrict__ b0, const float* __restrict__ W1,
    const float* __restrict__ b1, const float* __restrict__ Wout,
    const float* __restrict__ bout, float* __restrict__ out, int ntiles)
{
  // Weight staging ONLY (init, 16384 B). No H buffer.
  __shared__ __align__(16) _Float16 stage[2][2][4][64][8];

  const int tid  = threadIdx.x;
  const int wid  = tid >> 6;
  const int lane = tid & 63;
  const int m    = lane & 15;
  const int q    = lane >> 4;

  // ---- init: wave 0 builds the swizzled weight fragments ----
  // W0 (A-op, => W0^T): k=s*32+q*8+j, n=t*16+m; feature rows PERMUTED
  // (k-window 32..63 = [cos1..8|sin1..8|rho,b0(1.0),0pad]); pre-scaled by c.
  // W1 (A-op, => W1^T): rows hmap-permuted so L1's B-operand is L0's
  // register output directly: hmap(k) = (s*2+(j>>2))*16 + q*4 + (j&3).
  if (wid == 0) {
#pragma unroll
    for (int t = 0; t < 4; ++t) {
#pragma unroll
      for (int s = 0; s < 2; ++s) {
        half8 f0, f1;
#pragma unroll
        for (int j = 0; j < 8; ++j) {
          const int k = s * 32 + q * 8 + j;
          const int n = t * 16 + m;
          float v0;
          if (k < 32) {
            v0 = W0[k * 64 + n];
          } else {
            const int kn = k - 32;
            v0 = (kn < 16) ? W0[(33 + kn) * 64 + n]
               : (kn == 16) ? W0[32 * 64 + n]
               : (kn == 17) ? b0[n] : 0.0f;
          }
          f0[j] = (_Float16)(CSCL * v0);
          const int hm = (s * 2 + (j >> 2)) * 16 + q * 4 + (j & 3);
          f1[j] = (_Float16)W1[hm * 64 + n];   // W1 UNSCALED, hmap-permuted
        }
        *(half8*)&stage[0][s][t][lane][0] = f0;
        *(half8*)&stage[1][s][t][lane][0] = f1;
      }
    }
  }

  // ---- persistent epilogue constants, PACKED f16 (swapped L1 layout) ----
  half2v biash[8];   // c * b1[h],    h = t*16 + q*4 + r
  half2v wouth[8];   // -ln2 * Wout[h]
#pragma unroll
  for (int t = 0; t < 4; ++t) {
    const f32x4 bv = *(const f32x4*)(b1 + t * 16 + q * 4);
    const f32x4 wv = *(const f32x4*)(Wout + t * 16 + q * 4);
    biash[t * 2]     = pkh(CSCL * bv[0], CSCL * bv[1]);
    biash[t * 2 + 1] = pkh(CSCL * bv[2], CSCL * bv[3]);
    wouth[t * 2]     = pkh(NLN2 * wv[0], NLN2 * wv[1]);
    wouth[t * 2 + 1] = pkh(NLN2 * wv[2], NLN2 * wv[3]);
  }
  const float boutBL = bout[0] + BASE_LOGIT;

  __syncthreads();   // staged weights visible

  // ---- hoist ALL weight fragments to registers (loop-invariant) ----
  half8 w0A[4], w0B[4], w1A[4], w1B[4];
#pragma unroll
  for (int t = 0; t < 4; ++t) {
    w0A[t] = *(const half8*)&stage[0][0][t][lane][0];
    w0B[t] = *(const half8*)&stage[0][1][t][lane][0];
    w1A[t] = *(const half8*)&stage[1][0][t][lane][0];
    w1B[t] = *(const half8*)&stage[1][1][t][lane][0];
  }

  const f32x4 z = {0.0f, 0.0f, 0.0f, 0.0f};
  const int S = gridDim.x * 4;

  int tg = blockIdx.x * 4 + wid;
  if (tg >= ntiles) return;          // after the barrier: safe
  const int lim = ntiles - 1;

  // ---- phase1: feat -> L0 -> silu -> packed Y (registers only) ----
  auto phase1 = [&](float rhp, half8 X0v, H8& Y0o, H8& Y1o) {
    const float rev = 0.5f * rhp;  // v_sin/v_cos take revolutions
    const float c1  = __builtin_amdgcn_cosf(rev);
    const float s1f = __builtin_amdgcn_sinf(rev);
    const float tc  = 2.0f * c1;
    const float x1v = (q == 0) ? c1 : ((q == 1) ? s1f : 0.0f);
    const float x0v = (q == 0) ? 1.0f : 0.0f;
    const float x2v = tc * x1v - x0v;
    const float x3v = tc * x2v - x1v;
    const float x4v = tc * x3v - x2v;
    const float x5v = tc * x4v - x3v;
    const float x6v = tc * x5v - x4v;
    const float x7v = tc * x6v - x5v;
    const float x8v = tc * x7v - x6v;
    H8 X1;
    X1.v2[0] = (q == 2) ? pkh(rhp, 1.0f) : pkh(x1v, x2v);  // q==2: (rho, b0-slot)
    X1.v2[1] = pkh(x3v, x4v);
    X1.v2[2] = pkh(x5v, x6v);
    X1.v2[3] = pkh(x7v, x8v);

    f32x4 acc[4];
#pragma unroll
    for (int t = 0; t < 4; ++t) {
      f32x4 a = __builtin_amdgcn_mfma_f32_16x16x32_f16(w0A[t], X0v, z, 0, 0, 0);
      a = __builtin_amdgcn_mfma_f32_16x16x32_f16(w0B[t], X1.v8, a, 0, 0, 0);
      acc[t] = a;
    }
    H4 hh[4];
#pragma unroll
    for (int t = 0; t < 4; ++t) {
      float p0, p1, p2, p3;
      usilu2(acc[t][0], acc[t][1], p0, p1);
      usilu2(acc[t][2], acc[t][3], p2, p3);
      hh[t].v2[0] = pkh(p0, p1);
      hh[t].v2[1] = pkh(p2, p3);
    }
    Y0o.v4[0] = hh[0].v4; Y0o.v4[1] = hh[1].v4;   // hmap makes this exact
    Y1o.v4[0] = hh[2].v4; Y1o.v4[1] = hh[3].v4;
  };

  // ---- phase2: L1(carried Y) -> bias+silu -> dot -> reduce -> store ----
  auto phase2 = [&](const H8& Y0p, const H8& Y1p, int icP, int tgP) {
    f32x4 acc[4];
#pragma unroll
    for (int t = 0; t < 4; ++t) {
      f32x4 a = __builtin_amdgcn_mfma_f32_16x16x32_f16(w1A[t], Y0p.v8, z, 0, 0, 0);
      a = __builtin_amdgcn_mfma_f32_16x16x32_f16(w1B[t], Y1p.v8, a, 0, 0, 0);
      acc[t] = a;
    }
    float dA = 0.0f, dB = 0.0f;
#pragma unroll
    for (int t = 0; t < 4; ++t) {
      float p0, p1, p2, p3;
      const float u0 = (float)biash[t * 2][0]     + acc[t][0];  // v_fma_mix
      const float u1 = (float)biash[t * 2][1]     + acc[t][1];
      const float u2 = (float)biash[t * 2 + 1][0] + acc[t][2];
      const float u3 = (float)biash[t * 2 + 1][1] + acc[t][3];
      usilu2(u0, u1, p0, p1);
      usilu2(u2, u3, p2, p3);
      dA = fmaf(p0, (float)wouth[t * 2][0],     dA);
      dB = fmaf(p1, (float)wouth[t * 2][1],     dB);
      dA = fmaf(p2, (float)wouth[t * 2 + 1][0], dA);
      dB = fmaf(p3, (float)wouth[t * 2 + 1][1], dB);
    }
    float dot = dA + dB;
    dot += __shfl_xor(dot, 16, 64);
    dot += __shfl_xor(dot, 32, 64);
    const float theta = fast_rcp(1.0f + fast_exp2(-LOG2E * (dot + boutBL)));
    const float val = (icP == 0) ? IC_VAL : theta * CSANMAX;
    if (q == 0) out[tgP * 16 + m] = val;
  };

  // ---- prologue: run phase1 on tile tg; prep inputs for tile tg+S ----
  int   tC = tix[tg * 16 + m];
  float rC = rho[tg * 16 + m];
  const int tg1 = min(tg + S, lim);
  int   tN = tix[tg1 * 16 + m];
  float rN = rho[tg1 * 16 + m];
  H8 X0C;
  {
    const int idx = min(max(tC - 1, 0), 510);
    const float* e = emb + (size_t)idx * 32 + q * 8;
    const f32x4 e0 = *(const f32x4*)e;
    const f32x4 e1 = *(const f32x4*)(e + 4);
    X0C.v2[0] = pkh(e0[0], e0[1]); X0C.v2[1] = pkh(e0[2], e0[3]);
    X0C.v2[2] = pkh(e1[0], e1[1]); X0C.v2[3] = pkh(e1[2], e1[3]);
  }
  H8 Y0p, Y1p;
  phase1(rC, X0C.v8, Y0p, Y1p);
  int icP = tC, tgP = tg;
  {
    const int idx = min(max(tN - 1, 0), 510);
    const float* e = emb + (size_t)idx * 32 + q * 8;
    const f32x4 e0 = *(const f32x4*)e;
    const f32x4 e1 = *(const f32x4*)(e + 4);
    X0C.v2[0] = pkh(e0[0], e0[1]); X0C.v2[1] = pkh(e0[2], e0[3]);
    X0C.v2[2] = pkh(e1[0], e1[1]); X0C.v2[3] = pkh(e1[2], e1[3]);
  }
  tC = tN; rC = rN;
  {
    const int tg2 = min(tg + 2 * S, lim);
    tN = tix[tg2 * 16 + m];
    rN = rho[tg2 * 16 + m];
  }
  tg += S;

  // ---- steady state: phase2(tile k-1, carried Y) ; phase1(tile k) ----
  while (tg < ntiles) {
    // prefetch: tix/rho 2 tiles ahead; emb 1 tile ahead (tN is >=1 iter old)
    const int tg2 = min(tg + 2 * S, lim);
    const int   tQ = tix[tg2 * 16 + m];
    const float rQ = rho[tg2 * 16 + m];
    const int idxN = min(max(tN - 1, 0), 510);
    const float* ern = emb + (size_t)idxN * 32 + q * 8;
    const f32x4 eN0 = *(const f32x4*)ern;
    const f32x4 eN1 = *(const f32x4*)(ern + 4);

    phase2(Y0p, Y1p, icP, tgP);        // finish previous tile (reg-only deps)
    phase1(rC, X0C.v8, Y0p, Y1p);      // start current tile (independent)

    icP = tC; tgP = tg;
    X0C.v2[0] = pkh(eN0[0], eN0[1]); X0C.v2[1] = pkh(eN0[2], eN0[3]);
    X0C.v2[2] = pkh(eN1[0], eN1[1]); X0C.v2[3] = pkh(eN1[2], eN1[3]);
    tC = tN; rC = rN;
    tN = tQ; rN = rQ;
    tg += S;
  }

  // ---- epilogue: drain the last tile ----
  phase2(Y0p, Y1p, icP, tgP);
}

extern "C" void kernel_launch(void* const* d_in, const int* in_sizes, int n_in,
                              void* d_out, int out_size, void* d_ws, size_t ws_size,
                              hipStream_t stream) {
  const int*   tix  = (const int*)d_in[0];
  const float* rho  = (const float*)d_in[1];
  const float* emb  = (const float*)d_in[2];
  const float* W0   = (const float*)d_in[3];
  const float* b0   = (const float*)d_in[4];
  const float* W1   = (const float*)d_in[5];
  const float* b1   = (const float*)d_in[6];
  const float* Wout = (const float*)d_in[7];
  const float* bout = (const float*)d_in[8];
  float* outp = (float*)d_out;

  const int n      = in_sizes[0];    // 2,000,000 (divisible by 16)
  const int ntiles = n / 16;         // 125,000 tiles of 16 points

  // 4-wave blocks, 16384 B LDS (init staging only). Grid 1024 (R3 winner).
  int grid = 1024;
  const int maxg = (ntiles + 3) / 4;
  if (grid > maxg) grid = maxg;
  mlp_kernel<<<dim3(grid), dim3(256), 0, stream>>>(
      tix, rho, emb, W0, b0, W1, b1, Wout, bout, outp, ntiles);
}